// Round 1
// baseline (204.981 us; speedup 1.0000x reference)
//
#include <hip/hip_runtime.h>
#include <hip/hip_bf16.h>
#include <stdint.h>

typedef __attribute__((ext_vector_type(8))) short bf8;
typedef __attribute__((ext_vector_type(4))) float f4;

#define MFMA16(a, b, c) __builtin_amdgcn_mfma_f32_16x16x32_bf16((a), (b), (c), 0, 0, 0)

static __device__ __forceinline__ short f2b(float f) {
  uint32_t x = __float_as_uint(f);
  x += 0x7fffu + ((x >> 16) & 1u);
  return (short)(x >> 16);
}

// rope table: tab[s*32 + i] = (cos(s*invf_i), sin(s*invf_i)), s<2048, i<32
__global__ void rope_kernel(float2* __restrict__ tab) {
  const int t = blockIdx.x * 256 + threadIdx.x;
  const int s = t >> 5, i = t & 31;
  const float inv = powf(10000.0f, -(float)i * (1.0f / 32.0f));
  const float ang = (float)s * inv;
  float sv, cv;
  sincosf(ang, &sv, &cv);
  tab[t] = make_float2(cv, sv);
}

// C = A @ W^T, 128x128 tiles, BK=64, 4 waves each 64x64 (4x4 frags of 16x16x32).
// MODE 0: A = x (f32), W in {Wq,Wk,Wv} (f32) picked by blockIdx.z;
//         z<2: RoPE epilogue -> Q/K as [b][h][s][64] bf16
//         z==2: V^T epilogue -> [b][h][64][s] bf16
// MODE 1: A = AO (bf16), W = Wo (f32), f32 epilogue -> [m][n]
template <int MODE>
__launch_bounds__(256, 2)
__global__ void gemm_kernel(const void* __restrict__ Ap,
                            const float* __restrict__ W0f,
                            const float* __restrict__ W1f,
                            const float* __restrict__ W2f,
                            short* __restrict__ Qo, short* __restrict__ Ko,
                            short* __restrict__ VTo, float* __restrict__ Fo,
                            const float2* __restrict__ rope) {
  constexpr int K = 1024;
  const int bm = blockIdx.x, bn = blockIdx.y, z = blockIdx.z;
  const float* __restrict__ Bf =
      (MODE == 0) ? (z == 0 ? W0f : (z == 1 ? W1f : W2f)) : W0f;

  __shared__ short As[128 * 64];
  __shared__ short Bs[128 * 64];

  const int tid = threadIdx.x;
  const int lane = tid & 63;
  const int wave = tid >> 6;
  const int wr = wave >> 1, wc = wave & 1;
  const int lg = lane >> 4, lr = lane & 15;

  f4 acc[4][4];
#pragma unroll
  for (int i = 0; i < 4; i++)
#pragma unroll
    for (int j = 0; j < 4; j++) {
      acc[i][j][0] = 0.f; acc[i][j][1] = 0.f;
      acc[i][j][2] = 0.f; acc[i][j][3] = 0.f;
    }

  const int kc = tid & 7;     // 16B k-chunk within 64-wide slice
  const int srow = tid >> 3;  // 0..31

  for (int k0 = 0; k0 < K; k0 += 64) {
    bf8 va[4], vb[4];
#pragma unroll
    for (int i = 0; i < 4; i++) {
      const int row = srow + i * 32;
      if (MODE == 0) {
        const float* ga = (const float*)Ap + (size_t)(bm * 128 + row) * K + k0 + kc * 8;
        const float4 a0 = *(const float4*)ga;
        const float4 a1 = *(const float4*)(ga + 4);
        va[i][0] = f2b(a0.x); va[i][1] = f2b(a0.y); va[i][2] = f2b(a0.z); va[i][3] = f2b(a0.w);
        va[i][4] = f2b(a1.x); va[i][5] = f2b(a1.y); va[i][6] = f2b(a1.z); va[i][7] = f2b(a1.w);
      } else {
        va[i] = *(const bf8*)((const short*)Ap + (size_t)(bm * 128 + row) * K + k0 + kc * 8);
      }
      const float* gb = Bf + (size_t)(bn * 128 + row) * K + k0 + kc * 8;
      const float4 b0 = *(const float4*)gb;
      const float4 b1 = *(const float4*)(gb + 4);
      vb[i][0] = f2b(b0.x); vb[i][1] = f2b(b0.y); vb[i][2] = f2b(b0.z); vb[i][3] = f2b(b0.w);
      vb[i][4] = f2b(b1.x); vb[i][5] = f2b(b1.y); vb[i][6] = f2b(b1.z); vb[i][7] = f2b(b1.w);
    }
#pragma unroll
    for (int i = 0; i < 4; i++) {
      const int row = srow + i * 32;
      const int lb = (row * 128 + kc * 16) ^ ((row & 7) << 4);
      *(bf8*)((char*)As + lb) = va[i];
      *(bf8*)((char*)Bs + lb) = vb[i];
    }
    __syncthreads();
#pragma unroll
    for (int kk = 0; kk < 2; kk++) {
      bf8 af[4], bb[4];
#pragma unroll
      for (int mi = 0; mi < 4; mi++) {
        const int row = wr * 64 + mi * 16 + lr;
        const int lb = (row * 128 + kk * 64 + lg * 16) ^ ((row & 7) << 4);
        af[mi] = *(const bf8*)((const char*)As + lb);
      }
#pragma unroll
      for (int ni = 0; ni < 4; ni++) {
        const int row = wc * 64 + ni * 16 + lr;
        const int lb = (row * 128 + kk * 64 + lg * 16) ^ ((row & 7) << 4);
        bb[ni] = *(const bf8*)((const char*)Bs + lb);
      }
#pragma unroll
      for (int mi = 0; mi < 4; mi++)
#pragma unroll
        for (int ni = 0; ni < 4; ni++)
          acc[mi][ni] = MFMA16(af[mi], bb[ni], acc[mi][ni]);
    }
    __syncthreads();
  }

  if (MODE == 1) {
#pragma unroll
    for (int mi = 0; mi < 4; mi++) {
      const int m0 = bm * 128 + wr * 64 + mi * 16 + lg * 4;
#pragma unroll
      for (int ni = 0; ni < 4; ni++) {
        const int n = bn * 128 + wc * 64 + ni * 16 + lr;
#pragma unroll
        for (int r = 0; r < 4; r++)
          Fo[(size_t)(m0 + r) * 1024 + n] = acc[mi][ni][r];
      }
    }
    return;
  }

  if (z == 2) {  // V^T: [b][h][64][s]
#pragma unroll
    for (int mi = 0; mi < 4; mi++) {
      const int m0 = bm * 128 + wr * 64 + mi * 16 + lg * 4;
      const int b = m0 >> 11, s0 = m0 & 2047;
#pragma unroll
      for (int ni = 0; ni < 4; ni++) {
        const int n = bn * 128 + wc * 64 + ni * 16 + lr;
        ushort4 pk;
        pk.x = (unsigned short)f2b(acc[mi][ni][0]);
        pk.y = (unsigned short)f2b(acc[mi][ni][1]);
        pk.z = (unsigned short)f2b(acc[mi][ni][2]);
        pk.w = (unsigned short)f2b(acc[mi][ni][3]);
        *(ushort4*)(VTo + ((size_t)((b * 16 + (n >> 6)) * 64 + (n & 63))) * 2048 + s0) = pk;
      }
    }
  } else {  // Q or K with RoPE: [b][h][s][64]
    short* __restrict__ Out = (z == 0) ? Qo : Ko;
#pragma unroll
    for (int mi = 0; mi < 4; mi++) {
      const int m0 = bm * 128 + wr * 64 + mi * 16 + lg * 4;
      const int b = m0 >> 11, s0 = m0 & 2047;
#pragma unroll
      for (int ni = 0; ni < 4; ni++) {
        const int n = bn * 128 + wc * 64 + ni * 16 + lr;
        const int h = n >> 6, d = n & 63;
        const float sgn = (d & 1) ? 1.0f : -1.0f;
#pragma unroll
        for (int r = 0; r < 4; r++) {
          const float v = acc[mi][ni][r];
          const float p = __shfl_xor(v, 1);  // partner head-dim (d^1)
          const float2 cs = rope[((s0 + r) << 5) + (d >> 1)];
          const float res = v * cs.x + sgn * p * cs.y;
          Out[((size_t)(b * 16 + h) * 2048 + (s0 + r)) * 64 + d] = f2b(res);
        }
      }
    }
  }
}

// Flash attention, causal. 4 independent waves x 32 q-rows, KV blocks of 64.
// Q/K: [b][h][s][64] bf16; V: [b][h][64][s] bf16 (transposed); AO: [b][s][1024] bf16.
__launch_bounds__(256, 2)
__global__ void attn_kernel(const short* __restrict__ Qg, const short* __restrict__ Kg,
                            const short* __restrict__ Vg, short* __restrict__ AO) {
  const int S = 2048;
  const int bh = blockIdx.x, qi = blockIdx.y;
  const int lane = threadIdx.x & 63, wave = threadIdx.x >> 6;
  const int lg = lane >> 4, lr = lane & 15;
  const short* __restrict__ Qp = Qg + (size_t)bh * S * 64;
  const short* __restrict__ Kp = Kg + (size_t)bh * S * 64;
  const short* __restrict__ Vp = Vg + (size_t)bh * 64 * S;

  __shared__ short Pl[4][32 * 64];  // wave-private P tiles, XOR-swizzled
  char* const Pw = (char*)&Pl[wave][0];

  const int qbase = qi * 128 + wave * 32;

  bf8 qf[2][2];
#pragma unroll
  for (int mf = 0; mf < 2; mf++)
#pragma unroll
    for (int ks = 0; ks < 2; ks++)
      qf[mf][ks] = *(const bf8*)(Qp + (size_t)(qbase + mf * 16 + lr) * 64 + ks * 32 + lg * 8);

  f4 o[2][4];
  float mrun[2][4], lrun[2][4];
#pragma unroll
  for (int mf = 0; mf < 2; mf++) {
#pragma unroll
    for (int dt = 0; dt < 4; dt++) {
      o[mf][dt][0] = 0.f; o[mf][dt][1] = 0.f; o[mf][dt][2] = 0.f; o[mf][dt][3] = 0.f;
    }
#pragma unroll
    for (int r = 0; r < 4; r++) { mrun[mf][r] = -1e9f; lrun[mf][r] = 0.f; }
  }

  const int nkv = (qbase + 95) >> 6;  // per-wave causal trip count
  for (int kb = 0; kb < nkv; kb++) {
    const int kvb = kb * 64;

    bf8 kf[4][2];
#pragma unroll
    for (int nt = 0; nt < 4; nt++)
#pragma unroll
      for (int ks = 0; ks < 2; ks++)
        kf[nt][ks] = *(const bf8*)(Kp + (size_t)(kvb + nt * 16 + lr) * 64 + ks * 32 + lg * 8);

    f4 sc[2][4];
#pragma unroll
    for (int mf = 0; mf < 2; mf++)
#pragma unroll
      for (int nt = 0; nt < 4; nt++) {
        f4 c;
        c[0] = 0.f; c[1] = 0.f; c[2] = 0.f; c[3] = 0.f;
        c = MFMA16(qf[mf][0], kf[nt][0], c);
        c = MFMA16(qf[mf][1], kf[nt][1], c);
        sc[mf][nt] = c;
      }

    const bool need_mask = (kvb + 63) > qbase;

    // WAR guard: previous iteration's P reads fully drained (intra-wave)
    asm volatile("s_waitcnt lgkmcnt(0)" ::: "memory");

#pragma unroll
    for (int mf = 0; mf < 2; mf++) {
#pragma unroll
      for (int nt = 0; nt < 4; nt++)
#pragma unroll
        for (int r = 0; r < 4; r++) {
          float v = sc[mf][nt][r] * 0.125f;
          if (need_mask) {
            const int q = qbase + mf * 16 + lg * 4 + r;
            const int kv = kvb + nt * 16 + lr;
            if (kv > q) v = -1e9f;
          }
          sc[mf][nt][r] = v;
        }

      float corr[4], rs[4];
#pragma unroll
      for (int r = 0; r < 4; r++) {
        float t = fmaxf(fmaxf(sc[mf][0][r], sc[mf][1][r]), fmaxf(sc[mf][2][r], sc[mf][3][r]));
#pragma unroll
        for (int j = 0; j < 4; j++) t = fmaxf(t, __shfl_xor(t, 1 << j));
        const float mn = fmaxf(mrun[mf][r], t);
        corr[r] = __expf(mrun[mf][r] - mn);
        mrun[mf][r] = mn;
        rs[r] = 0.f;
      }
#pragma unroll
      for (int nt = 0; nt < 4; nt++)
#pragma unroll
        for (int r = 0; r < 4; r++) {
          const float p = __expf(sc[mf][nt][r] - mrun[mf][r]);
          rs[r] += p;
          const int row = mf * 16 + lg * 4 + r;
          const int boff = (row * 128 + (nt * 16 + lr) * 2) ^ ((row & 7) << 4);
          *(short*)(Pw + boff) = f2b(p);
        }
#pragma unroll
      for (int r = 0; r < 4; r++) {
        float t = rs[r];
#pragma unroll
        for (int j = 0; j < 4; j++) t += __shfl_xor(t, 1 << j);
        lrun[mf][r] = lrun[mf][r] * corr[r] + t;
      }
#pragma unroll
      for (int dt = 0; dt < 4; dt++)
#pragma unroll
        for (int r = 0; r < 4; r++) o[mf][dt][r] *= corr[r];
    }

    // RAW guard: all lanes' P writes visible before fragment reads
    asm volatile("s_waitcnt lgkmcnt(0)" ::: "memory");

    bf8 vf[4][2];
#pragma unroll
    for (int dt = 0; dt < 4; dt++)
#pragma unroll
      for (int ks = 0; ks < 2; ks++)
        vf[dt][ks] = *(const bf8*)(Vp + (size_t)(dt * 16 + lr) * S + kvb + ks * 32 + lg * 8);

#pragma unroll
    for (int mf = 0; mf < 2; mf++) {
      bf8 pf[2];
#pragma unroll
      for (int ks = 0; ks < 2; ks++) {
        const int row = mf * 16 + lr;
        const int boff = (row * 128 + ks * 64 + lg * 16) ^ ((row & 7) << 4);
        pf[ks] = *(const bf8*)(Pw + boff);
      }
#pragma unroll
      for (int dt = 0; dt < 4; dt++) {
        o[mf][dt] = MFMA16(pf[0], vf[dt][0], o[mf][dt]);
        o[mf][dt] = MFMA16(pf[1], vf[dt][1], o[mf][dt]);
      }
    }
  }

  const int b = bh >> 4, h = bh & 15;
#pragma unroll
  for (int mf = 0; mf < 2; mf++)
#pragma unroll
    for (int r = 0; r < 4; r++) {
      const int q = qbase + mf * 16 + lg * 4 + r;
      const float inv = 1.0f / lrun[mf][r];
#pragma unroll
      for (int dt = 0; dt < 4; dt++) {
        const int d = dt * 16 + lr;
        AO[((size_t)b * 2048 + q) * 1024 + h * 64 + d] = f2b(o[mf][dt][r] * inv);
      }
    }
}

extern "C" void kernel_launch(void* const* d_in, const int* in_sizes, int n_in,
                              void* d_out, int out_size, void* d_ws, size_t ws_size,
                              hipStream_t stream) {
  const float* x  = (const float*)d_in[0];
  const float* wq = (const float*)d_in[1];
  const float* wk = (const float*)d_in[2];
  const float* wv = (const float*)d_in[3];
  const float* wo = (const float*)d_in[4];
  float* out = (float*)d_out;

  char* ws = (char*)d_ws;
  short*  Qb  = (short*)(ws);                       // 8 MB  [b][h][s][64] bf16
  short*  Kb  = (short*)(ws + (8ull  << 20));       // 8 MB
  short*  VTb = (short*)(ws + (16ull << 20));       // 8 MB  [b][h][64][s] bf16
  short*  AOb = (short*)(ws + (24ull << 20));       // 8 MB  [b][s][1024] bf16
  float2* tab = (float2*)(ws + (32ull << 20));      // 512 KB rope table

  rope_kernel<<<256, 256, 0, stream>>>(tab);
  gemm_kernel<0><<<dim3(32, 8, 3), 256, 0, stream>>>(
      x, wq, wk, wv, Qb, Kb, VTb, nullptr, tab);
  attn_kernel<<<dim3(32, 16), 256, 0, stream>>>(Qb, Kb, VTb, AOb);
  gemm_kernel<1><<<dim3(32, 8, 1), 256, 0, stream>>>(
      AOb, wo, wo, wo, nullptr, nullptr, nullptr, out, nullptr);
}

// Round 2
// 193.796 us; speedup vs baseline: 1.0577x; 1.0577x over previous
//
#include <hip/hip_runtime.h>
#include <hip/hip_bf16.h>
#include <stdint.h>

typedef __attribute__((ext_vector_type(8))) short bf8;
typedef __attribute__((ext_vector_type(4))) float f4;

#define MFMA16(a, b, c) __builtin_amdgcn_mfma_f32_16x16x32_bf16((a), (b), (c), 0, 0, 0)

static __device__ __forceinline__ short f2b(float f) {
  uint32_t x = __float_as_uint(f);
  x += 0x7fffu + ((x >> 16) & 1u);
  return (short)(x >> 16);
}

// cheap round-half-up f32->bf16 (P values are nonnegative; bias < 0.5 ulp)
static __device__ __forceinline__ short f2b_fast(float f) {
  return (short)((__float_as_uint(f) + 0x8000u) >> 16);
}

// rope table: tab[s*32 + i] = (cos(s*invf_i), sin(s*invf_i)), s<2048, i<32
__global__ void rope_kernel(float2* __restrict__ tab) {
  const int t = blockIdx.x * 256 + threadIdx.x;
  const int s = t >> 5, i = t & 31;
  const float inv = powf(10000.0f, -(float)i * (1.0f / 32.0f));
  const float ang = (float)s * inv;
  float sv, cv;
  sincosf(ang, &sv, &cv);
  tab[t] = make_float2(cv, sv);
}

// C = A @ W^T, 128x128 tiles, BK=64, 4 waves each 64x64 (4x4 frags of 16x16x32).
// MODE 0: A = x (f32), W in {Wq,Wk,Wv} (f32) picked by blockIdx.z;
//         z<2: RoPE epilogue -> Q/K as [b][h][s][64] bf16 (Q pre-scaled by 0.125*log2e)
//         z==2: V^T epilogue -> [b][h][64][s] bf16
// MODE 1: A = AO (bf16), W = Wo (f32), f32 epilogue -> [m][n]
template <int MODE>
__launch_bounds__(256, 2)
__global__ void gemm_kernel(const void* __restrict__ Ap,
                            const float* __restrict__ W0f,
                            const float* __restrict__ W1f,
                            const float* __restrict__ W2f,
                            short* __restrict__ Qo, short* __restrict__ Ko,
                            short* __restrict__ VTo, float* __restrict__ Fo,
                            const float2* __restrict__ rope) {
  constexpr int K = 1024;
  const int bm = blockIdx.x, bn = blockIdx.y, z = blockIdx.z;
  const float* __restrict__ Bf =
      (MODE == 0) ? (z == 0 ? W0f : (z == 1 ? W1f : W2f)) : W0f;

  __shared__ short As[128 * 64];
  __shared__ short Bs[128 * 64];

  const int tid = threadIdx.x;
  const int lane = tid & 63;
  const int wave = tid >> 6;
  const int wr = wave >> 1, wc = wave & 1;
  const int lg = lane >> 4, lr = lane & 15;

  f4 acc[4][4];
#pragma unroll
  for (int i = 0; i < 4; i++)
#pragma unroll
    for (int j = 0; j < 4; j++) {
      acc[i][j][0] = 0.f; acc[i][j][1] = 0.f;
      acc[i][j][2] = 0.f; acc[i][j][3] = 0.f;
    }

  const int kc = tid & 7;     // 16B k-chunk within 64-wide slice
  const int srow = tid >> 3;  // 0..31

  for (int k0 = 0; k0 < K; k0 += 64) {
    bf8 va[4], vb[4];
#pragma unroll
    for (int i = 0; i < 4; i++) {
      const int row = srow + i * 32;
      if (MODE == 0) {
        const float* ga = (const float*)Ap + (size_t)(bm * 128 + row) * K + k0 + kc * 8;
        const float4 a0 = *(const float4*)ga;
        const float4 a1 = *(const float4*)(ga + 4);
        va[i][0] = f2b(a0.x); va[i][1] = f2b(a0.y); va[i][2] = f2b(a0.z); va[i][3] = f2b(a0.w);
        va[i][4] = f2b(a1.x); va[i][5] = f2b(a1.y); va[i][6] = f2b(a1.z); va[i][7] = f2b(a1.w);
      } else {
        va[i] = *(const bf8*)((const short*)Ap + (size_t)(bm * 128 + row) * K + k0 + kc * 8);
      }
      const float* gb = Bf + (size_t)(bn * 128 + row) * K + k0 + kc * 8;
      const float4 b0 = *(const float4*)gb;
      const float4 b1 = *(const float4*)(gb + 4);
      vb[i][0] = f2b(b0.x); vb[i][1] = f2b(b0.y); vb[i][2] = f2b(b0.z); vb[i][3] = f2b(b0.w);
      vb[i][4] = f2b(b1.x); vb[i][5] = f2b(b1.y); vb[i][6] = f2b(b1.z); vb[i][7] = f2b(b1.w);
    }
#pragma unroll
    for (int i = 0; i < 4; i++) {
      const int row = srow + i * 32;
      const int lb = (row * 128 + kc * 16) ^ ((row & 7) << 4);
      *(bf8*)((char*)As + lb) = va[i];
      *(bf8*)((char*)Bs + lb) = vb[i];
    }
    __syncthreads();
#pragma unroll
    for (int kk = 0; kk < 2; kk++) {
      bf8 af[4], bb[4];
#pragma unroll
      for (int mi = 0; mi < 4; mi++) {
        const int row = wr * 64 + mi * 16 + lr;
        const int lb = (row * 128 + kk * 64 + lg * 16) ^ ((row & 7) << 4);
        af[mi] = *(const bf8*)((const char*)As + lb);
      }
#pragma unroll
      for (int ni = 0; ni < 4; ni++) {
        const int row = wc * 64 + ni * 16 + lr;
        const int lb = (row * 128 + kk * 64 + lg * 16) ^ ((row & 7) << 4);
        bb[ni] = *(const bf8*)((const char*)Bs + lb);
      }
#pragma unroll
      for (int mi = 0; mi < 4; mi++)
#pragma unroll
        for (int ni = 0; ni < 4; ni++)
          acc[mi][ni] = MFMA16(af[mi], bb[ni], acc[mi][ni]);
    }
    __syncthreads();
  }

  if (MODE == 1) {
#pragma unroll
    for (int mi = 0; mi < 4; mi++) {
      const int m0 = bm * 128 + wr * 64 + mi * 16 + lg * 4;
#pragma unroll
      for (int ni = 0; ni < 4; ni++) {
        const int n = bn * 128 + wc * 64 + ni * 16 + lr;
#pragma unroll
        for (int r = 0; r < 4; r++)
          Fo[(size_t)(m0 + r) * 1024 + n] = acc[mi][ni][r];
      }
    }
    return;
  }

  if (z == 2) {  // V^T: [b][h][64][s]
#pragma unroll
    for (int mi = 0; mi < 4; mi++) {
      const int m0 = bm * 128 + wr * 64 + mi * 16 + lg * 4;
      const int b = m0 >> 11, s0 = m0 & 2047;
#pragma unroll
      for (int ni = 0; ni < 4; ni++) {
        const int n = bn * 128 + wc * 64 + ni * 16 + lr;
        ushort4 pk;
        pk.x = (unsigned short)f2b(acc[mi][ni][0]);
        pk.y = (unsigned short)f2b(acc[mi][ni][1]);
        pk.z = (unsigned short)f2b(acc[mi][ni][2]);
        pk.w = (unsigned short)f2b(acc[mi][ni][3]);
        *(ushort4*)(VTo + ((size_t)((b * 16 + (n >> 6)) * 64 + (n & 63))) * 2048 + s0) = pk;
      }
    }
  } else {  // Q or K with RoPE: [b][h][s][64]
    short* __restrict__ Out = (z == 0) ? Qo : Ko;
    // Q gets the attention scale folded with log2(e) so softmax can use exp2
    const float qscale = (z == 0) ? 0.18033688011112042f : 1.0f;  // 0.125*log2(e)
#pragma unroll
    for (int mi = 0; mi < 4; mi++) {
      const int m0 = bm * 128 + wr * 64 + mi * 16 + lg * 4;
      const int b = m0 >> 11, s0 = m0 & 2047;
#pragma unroll
      for (int ni = 0; ni < 4; ni++) {
        const int n = bn * 128 + wc * 64 + ni * 16 + lr;
        const int h = n >> 6, d = n & 63;
        const float sgn = (d & 1) ? 1.0f : -1.0f;
#pragma unroll
        for (int r = 0; r < 4; r++) {
          const float v = acc[mi][ni][r];
          const float p = __shfl_xor(v, 1);  // partner head-dim (d^1)
          const float2 cs = rope[((s0 + r) << 5) + (d >> 1)];
          const float res = (v * cs.x + sgn * p * cs.y) * qscale;
          Out[((size_t)(b * 16 + h) * 2048 + (s0 + r)) * 64 + d] = f2b(res);
        }
      }
    }
  }
}

// Flash attention, causal. 4 waves/block; each wave owns one 32-row q-tile.
// Tile assignment balances total work per block exactly: {qi, 31-qi, 32+qi, 63-qi},
// rotated across wave slots so long tiles spread over SIMDs.
// Q pre-scaled by 0.125*log2e -> softmax in log2 domain (v_exp directly).
// Q/K: [b][h][s][64] bf16; V: [b][h][64][s] bf16 (transposed); AO: [b][s][1024] bf16.
__launch_bounds__(256, 2)
__global__ void attn_kernel(const short* __restrict__ Qg, const short* __restrict__ Kg,
                            const short* __restrict__ Vg, short* __restrict__ AO) {
  const int S = 2048;
  const int bh = blockIdx.x, qi = blockIdx.y;
  const int lane = threadIdx.x & 63, wave = threadIdx.x >> 6;
  const int lg = lane >> 4, lr = lane & 15;
  const short* __restrict__ Qp = Qg + (size_t)bh * S * 64;
  const short* __restrict__ Kp = Kg + (size_t)bh * S * 64;
  const short* __restrict__ Vp = Vg + (size_t)bh * 64 * S;

  __shared__ short Pl[4][32 * 64];  // wave-private P tiles, XOR-swizzled
  char* const Pw = (char*)&Pl[wave][0];

  const int slot = (wave + qi) & 3;
  const int t = (slot == 0) ? qi : (slot == 1) ? (31 - qi)
              : (slot == 2) ? (32 + qi) : (63 - qi);
  const int qbase = t << 5;

  bf8 qf[2][2];
#pragma unroll
  for (int mf = 0; mf < 2; mf++)
#pragma unroll
    for (int ks = 0; ks < 2; ks++)
      qf[mf][ks] = *(const bf8*)(Qp + (size_t)(qbase + mf * 16 + lr) * 64 + ks * 32 + lg * 8);

  f4 o[2][4];
  float mrun[2][4], lsum[2][4];
#pragma unroll
  for (int mf = 0; mf < 2; mf++) {
#pragma unroll
    for (int dt = 0; dt < 4; dt++) {
      o[mf][dt][0] = 0.f; o[mf][dt][1] = 0.f; o[mf][dt][2] = 0.f; o[mf][dt][3] = 0.f;
    }
#pragma unroll
    for (int r = 0; r < 4; r++) { mrun[mf][r] = -1e30f; lsum[mf][r] = 0.f; }
  }

  const int nkv = (qbase + 95) >> 6;  // causal trip count for this tile
  for (int kb = 0; kb < nkv; kb++) {
    const int kvb = kb * 64;

    bf8 kf[4][2];
#pragma unroll
    for (int nt = 0; nt < 4; nt++)
#pragma unroll
      for (int ks = 0; ks < 2; ks++)
        kf[nt][ks] = *(const bf8*)(Kp + (size_t)(kvb + nt * 16 + lr) * 64 + ks * 32 + lg * 8);

    f4 sc[2][4];
    __builtin_amdgcn_s_setprio(1);
#pragma unroll
    for (int mf = 0; mf < 2; mf++)
#pragma unroll
      for (int nt = 0; nt < 4; nt++) {
        f4 c;
        c[0] = 0.f; c[1] = 0.f; c[2] = 0.f; c[3] = 0.f;
        c = MFMA16(qf[mf][0], kf[nt][0], c);
        c = MFMA16(qf[mf][1], kf[nt][1], c);
        sc[mf][nt] = c;
      }
    __builtin_amdgcn_s_setprio(0);

    const bool need_mask = (kvb + 63) > qbase;
    if (need_mask) {
#pragma unroll
      for (int mf = 0; mf < 2; mf++)
#pragma unroll
        for (int nt = 0; nt < 4; nt++)
#pragma unroll
          for (int r = 0; r < 4; r++) {
            const int q = qbase + mf * 16 + lg * 4 + r;
            const int kv = kvb + nt * 16 + lr;
            if (kv > q) sc[mf][nt][r] = -1e9f;
          }
    }

    // WAR guard: previous iteration's P reads fully drained (intra-wave)
    asm volatile("s_waitcnt lgkmcnt(0)" ::: "memory");

#pragma unroll
    for (int mf = 0; mf < 2; mf++) {
      // per-row tile max (cross-lane over the 16-lane row slice)
      float tmax[4];
#pragma unroll
      for (int r = 0; r < 4; r++) {
        float m0 = fmaxf(fmaxf(sc[mf][0][r], sc[mf][1][r]), fmaxf(sc[mf][2][r], sc[mf][3][r]));
#pragma unroll
        for (int j = 0; j < 4; j++) m0 = fmaxf(m0, __shfl_xor(m0, 1 << j));
        tmax[r] = m0;
      }
      // defer-max: only rescale when tile max grew past threshold (log2 domain)
      float g = tmax[0] - mrun[mf][0];
#pragma unroll
      for (int r = 1; r < 4; r++) g = fmaxf(g, tmax[r] - mrun[mf][r]);
      if (__any(g > 8.0f)) {
#pragma unroll
        for (int r = 0; r < 4; r++) {
          const float mn = fmaxf(mrun[mf][r], tmax[r]);
          const float corr = __builtin_amdgcn_exp2f(mrun[mf][r] - mn);
          mrun[mf][r] = mn;
          lsum[mf][r] *= corr;
#pragma unroll
          for (int dt = 0; dt < 4; dt++) o[mf][dt][r] *= corr;
        }
      }
      // P = exp2(sc - m); accumulate per-lane partial sums; store bf16 to LDS
#pragma unroll
      for (int nt = 0; nt < 4; nt++)
#pragma unroll
        for (int r = 0; r < 4; r++) {
          const float p = __builtin_amdgcn_exp2f(sc[mf][nt][r] - mrun[mf][r]);
          lsum[mf][r] += p;
          const int row = mf * 16 + lg * 4 + r;
          const int boff = (row * 128 + (nt * 16 + lr) * 2) ^ ((row & 7) << 4);
          *(short*)(Pw + boff) = f2b_fast(p);
        }
    }

    // RAW guard: all lanes' P writes visible before fragment reads
    asm volatile("s_waitcnt lgkmcnt(0)" ::: "memory");

    bf8 vf[4][2];
#pragma unroll
    for (int dt = 0; dt < 4; dt++)
#pragma unroll
      for (int ks = 0; ks < 2; ks++)
        vf[dt][ks] = *(const bf8*)(Vp + (size_t)(dt * 16 + lr) * S + kvb + ks * 32 + lg * 8);

#pragma unroll
    for (int mf = 0; mf < 2; mf++) {
      bf8 pf[2];
#pragma unroll
      for (int ks = 0; ks < 2; ks++) {
        const int row = mf * 16 + lr;
        const int boff = (row * 128 + ks * 64 + lg * 16) ^ ((row & 7) << 4);
        pf[ks] = *(const bf8*)(Pw + boff);
      }
      __builtin_amdgcn_s_setprio(1);
#pragma unroll
      for (int dt = 0; dt < 4; dt++) {
        o[mf][dt] = MFMA16(pf[0], vf[dt][0], o[mf][dt]);
        o[mf][dt] = MFMA16(pf[1], vf[dt][1], o[mf][dt]);
      }
      __builtin_amdgcn_s_setprio(0);
    }
  }

  // final cross-lane row-sum reduce (deferred from the main loop)
#pragma unroll
  for (int mf = 0; mf < 2; mf++)
#pragma unroll
    for (int r = 0; r < 4; r++) {
      float s = lsum[mf][r];
#pragma unroll
      for (int j = 0; j < 4; j++) s += __shfl_xor(s, 1 << j);
      lsum[mf][r] = s;
    }

  const int b = bh >> 4, h = bh & 15;
#pragma unroll
  for (int mf = 0; mf < 2; mf++)
#pragma unroll
    for (int r = 0; r < 4; r++) {
      const int q = qbase + mf * 16 + lg * 4 + r;
      const float inv = 1.0f / lsum[mf][r];
#pragma unroll
      for (int dt = 0; dt < 4; dt++) {
        const int d = dt * 16 + lr;
        AO[((size_t)b * 2048 + q) * 1024 + h * 64 + d] = f2b(o[mf][dt][r] * inv);
      }
    }
}

extern "C" void kernel_launch(void* const* d_in, const int* in_sizes, int n_in,
                              void* d_out, int out_size, void* d_ws, size_t ws_size,
                              hipStream_t stream) {
  const float* x  = (const float*)d_in[0];
  const float* wq = (const float*)d_in[1];
  const float* wk = (const float*)d_in[2];
  const float* wv = (const float*)d_in[3];
  const float* wo = (const float*)d_in[4];
  float* out = (float*)d_out;

  char* ws = (char*)d_ws;
  short*  Qb  = (short*)(ws);                       // 8 MB  [b][h][s][64] bf16 (pre-scaled)
  short*  Kb  = (short*)(ws + (8ull  << 20));       // 8 MB
  short*  VTb = (short*)(ws + (16ull << 20));       // 8 MB  [b][h][64][s] bf16
  short*  AOb = (short*)(ws + (24ull << 20));       // 8 MB  [b][s][1024] bf16
  float2* tab = (float2*)(ws + (32ull << 20));      // 512 KB rope table

  rope_kernel<<<256, 256, 0, stream>>>(tab);
  gemm_kernel<0><<<dim3(32, 8, 3), 256, 0, stream>>>(
      x, wq, wk, wv, Qb, Kb, VTb, nullptr, tab);
  attn_kernel<<<dim3(32, 16), 256, 0, stream>>>(Qb, Kb, VTb, AOb);
  gemm_kernel<1><<<dim3(32, 8, 1), 256, 0, stream>>>(
      AOb, wo, wo, wo, nullptr, nullptr, nullptr, out, nullptr);
}

// Round 3
// 181.351 us; speedup vs baseline: 1.1303x; 1.0686x over previous
//
#include <hip/hip_runtime.h>
#include <hip/hip_bf16.h>
#include <stdint.h>

typedef __attribute__((ext_vector_type(8))) short bf8;
typedef __attribute__((ext_vector_type(4))) float f4;

#define MFMA16(a, b, c) __builtin_amdgcn_mfma_f32_16x16x32_bf16((a), (b), (c), 0, 0, 0)

static __device__ __forceinline__ short f2b(float f) {
  uint32_t x = __float_as_uint(f);
  x += 0x7fffu + ((x >> 16) & 1u);
  return (short)(x >> 16);
}

// cheap round-half-up f32->bf16 (P values are nonnegative; bias < 0.5 ulp)
static __device__ __forceinline__ short f2b_fast(float f) {
  return (short)((__float_as_uint(f) + 0x8000u) >> 16);
}

// rope table: tab[s*32 + i] = (cos(s*invf_i), sin(s*invf_i)), s<2048, i<32
__global__ void rope_kernel(float2* __restrict__ tab) {
  const int t = blockIdx.x * 256 + threadIdx.x;
  const int s = t >> 5, i = t & 31;
  const float inv = powf(10000.0f, -(float)i * (1.0f / 32.0f));
  const float ang = (float)s * inv;
  float sv, cv;
  sincosf(ang, &sv, &cv);
  tab[t] = make_float2(cv, sv);
}

// one-shot f32->bf16: x (4194304) -> xb; wq,wk,wv,wo (1048576 each) -> Wb[4][1<<20]
__global__ void convert_kernel(const float* __restrict__ x,
                               const float* __restrict__ wq, const float* __restrict__ wk,
                               const float* __restrict__ wv, const float* __restrict__ wo,
                               short* __restrict__ xb, short* __restrict__ Wb) {
  const size_t i = ((size_t)blockIdx.x * 256 + threadIdx.x) * 8;
  const float* __restrict__ src;
  short* __restrict__ dst;
  if (i < 4194304u) {
    src = x + i;
    dst = xb + i;
  } else {
    const size_t j = i - 4194304u;
    const int z = (int)(j >> 20);
    const size_t o = j & 1048575u;
    src = (z == 0 ? wq : z == 1 ? wk : z == 2 ? wv : wo) + o;
    dst = Wb + j;
  }
  const float4 a = *(const float4*)src;
  const float4 b = *(const float4*)(src + 4);
  bf8 v;
  v[0] = f2b(a.x); v[1] = f2b(a.y); v[2] = f2b(a.z); v[3] = f2b(a.w);
  v[4] = f2b(b.x); v[5] = f2b(b.y); v[6] = f2b(b.z); v[7] = f2b(b.w);
  *(bf8*)dst = v;
}

// C = A @ W^T, pure-bf16 inputs. 128x128 tiles, BK=64, 4 waves each 64x64.
// MODE 0: A = xb, W = Wb[z] (z = blockIdx.z in {0,1,2} = Wq,Wk,Wv)
//         z<2: RoPE epilogue -> Q/K as [b][h][s][64] bf16 (Q pre-scaled by 0.125*log2e)
//         z==2: V^T epilogue -> [b][h][64][s] bf16
// MODE 1: A = AOb, W = Wb[3] (Wo), f32 epilogue -> [m][n]
template <int MODE>
__launch_bounds__(256, 2)
__global__ void gemm_kernel(const short* __restrict__ Ab, const short* __restrict__ Wb,
                            short* __restrict__ Qo, short* __restrict__ Ko,
                            short* __restrict__ VTo, float* __restrict__ Fo,
                            const float2* __restrict__ rope) {
  constexpr int K = 1024;
  const int bm = blockIdx.x, bn = blockIdx.y;
  const int z = (MODE == 0) ? blockIdx.z : 3;
  const short* __restrict__ Bb = Wb + ((size_t)z << 20);

  __shared__ short As[128 * 64];
  __shared__ short Bs[128 * 64];

  const int tid = threadIdx.x;
  const int lane = tid & 63;
  const int wave = tid >> 6;
  const int wr = wave >> 1, wc = wave & 1;
  const int lg = lane >> 4, lr = lane & 15;

  f4 acc[4][4];
#pragma unroll
  for (int i = 0; i < 4; i++)
#pragma unroll
    for (int j = 0; j < 4; j++) {
      acc[i][j][0] = 0.f; acc[i][j][1] = 0.f;
      acc[i][j][2] = 0.f; acc[i][j][3] = 0.f;
    }

  const int kc = tid & 7;     // 16B k-chunk within 64-wide slice
  const int srow = tid >> 3;  // 0..31

  for (int k0 = 0; k0 < K; k0 += 64) {
    bf8 va[4], vb[4];
#pragma unroll
    for (int i = 0; i < 4; i++) {
      const int row = srow + i * 32;
      va[i] = *(const bf8*)(Ab + (size_t)(bm * 128 + row) * K + k0 + kc * 8);
      vb[i] = *(const bf8*)(Bb + (size_t)(bn * 128 + row) * K + k0 + kc * 8);
    }
#pragma unroll
    for (int i = 0; i < 4; i++) {
      const int row = srow + i * 32;
      const int lb = (row * 128 + kc * 16) ^ ((row & 7) << 4);
      *(bf8*)((char*)As + lb) = va[i];
      *(bf8*)((char*)Bs + lb) = vb[i];
    }
    __syncthreads();
#pragma unroll
    for (int kk = 0; kk < 2; kk++) {
      bf8 af[4], bb[4];
#pragma unroll
      for (int mi = 0; mi < 4; mi++) {
        const int row = wr * 64 + mi * 16 + lr;
        const int lb = (row * 128 + kk * 64 + lg * 16) ^ ((row & 7) << 4);
        af[mi] = *(const bf8*)((const char*)As + lb);
      }
#pragma unroll
      for (int ni = 0; ni < 4; ni++) {
        const int row = wc * 64 + ni * 16 + lr;
        const int lb = (row * 128 + kk * 64 + lg * 16) ^ ((row & 7) << 4);
        bb[ni] = *(const bf8*)((const char*)Bs + lb);
      }
      __builtin_amdgcn_s_setprio(1);
#pragma unroll
      for (int mi = 0; mi < 4; mi++)
#pragma unroll
        for (int ni = 0; ni < 4; ni++)
          acc[mi][ni] = MFMA16(af[mi], bb[ni], acc[mi][ni]);
      __builtin_amdgcn_s_setprio(0);
    }
    __syncthreads();
  }

  if (MODE == 1) {
#pragma unroll
    for (int mi = 0; mi < 4; mi++) {
      const int m0 = bm * 128 + wr * 64 + mi * 16 + lg * 4;
#pragma unroll
      for (int ni = 0; ni < 4; ni++) {
        const int n = bn * 128 + wc * 64 + ni * 16 + lr;
#pragma unroll
        for (int r = 0; r < 4; r++)
          Fo[(size_t)(m0 + r) * 1024 + n] = acc[mi][ni][r];
      }
    }
    return;
  }

  if (z == 2) {  // V^T: [b][h][64][s]
#pragma unroll
    for (int mi = 0; mi < 4; mi++) {
      const int m0 = bm * 128 + wr * 64 + mi * 16 + lg * 4;
      const int b = m0 >> 11, s0 = m0 & 2047;
#pragma unroll
      for (int ni = 0; ni < 4; ni++) {
        const int n = bn * 128 + wc * 64 + ni * 16 + lr;
        ushort4 pk;
        pk.x = (unsigned short)f2b(acc[mi][ni][0]);
        pk.y = (unsigned short)f2b(acc[mi][ni][1]);
        pk.z = (unsigned short)f2b(acc[mi][ni][2]);
        pk.w = (unsigned short)f2b(acc[mi][ni][3]);
        *(ushort4*)(VTo + ((size_t)((b * 16 + (n >> 6)) * 64 + (n & 63))) * 2048 + s0) = pk;
      }
    }
  } else {  // Q or K with RoPE: [b][h][s][64]
    short* __restrict__ Out = (z == 0) ? Qo : Ko;
    // Q gets the attention scale folded with log2(e) so softmax can use exp2
    const float qscale = (z == 0) ? 0.18033688011112042f : 1.0f;  // 0.125*log2(e)
#pragma unroll
    for (int mi = 0; mi < 4; mi++) {
      const int m0 = bm * 128 + wr * 64 + mi * 16 + lg * 4;
      const int b = m0 >> 11, s0 = m0 & 2047;
#pragma unroll
      for (int ni = 0; ni < 4; ni++) {
        const int n = bn * 128 + wc * 64 + ni * 16 + lr;
        const int h = n >> 6, d = n & 63;
        const float sgn = (d & 1) ? 1.0f : -1.0f;
#pragma unroll
        for (int r = 0; r < 4; r++) {
          const float v = acc[mi][ni][r];
          const float p = __shfl_xor(v, 1);  // partner head-dim (d^1)
          const float2 cs = rope[((s0 + r) << 5) + (d >> 1)];
          const float res = (v * cs.x + sgn * p * cs.y) * qscale;
          Out[((size_t)(b * 16 + h) * 2048 + (s0 + r)) * 64 + d] = f2b(res);
        }
      }
    }
  }
}

// Flash attention, causal. 4 waves/block; each wave owns one 32-row q-tile.
// Balanced tile set per block {qi, 31-qi, 32+qi, 63-qi}, rotated across wave slots.
// Software pipeline: V issued at iter start (hidden by QK+softmax); K[kb+1]
// prefetched into alternate regs after QK (hidden by softmax+PV).
// Q pre-scaled by 0.125*log2e -> softmax in exp2 domain.
__launch_bounds__(256, 2)
__global__ void attn_kernel(const short* __restrict__ Qg, const short* __restrict__ Kg,
                            const short* __restrict__ Vg, short* __restrict__ AO) {
  const int S = 2048;
  const int bh = blockIdx.x, qi = blockIdx.y;
  const int lane = threadIdx.x & 63, wave = threadIdx.x >> 6;
  const int lg = lane >> 4, lr = lane & 15;
  const short* __restrict__ Qp = Qg + (size_t)bh * S * 64;
  const short* __restrict__ Kp = Kg + (size_t)bh * S * 64;
  const short* __restrict__ Vp = Vg + (size_t)bh * 64 * S;

  __shared__ short Pl[4][32 * 64];  // wave-private P tiles, XOR-swizzled
  char* const Pw = (char*)&Pl[wave][0];

  const int slot = (wave + qi) & 3;
  const int t = (slot == 0) ? qi : (slot == 1) ? (31 - qi)
              : (slot == 2) ? (32 + qi) : (63 - qi);
  const int qbase = t << 5;

  bf8 qf[2][2];
#pragma unroll
  for (int mf = 0; mf < 2; mf++)
#pragma unroll
    for (int ks = 0; ks < 2; ks++)
      qf[mf][ks] = *(const bf8*)(Qp + (size_t)(qbase + mf * 16 + lr) * 64 + ks * 32 + lg * 8);

  f4 o[2][4];
  float mrun[2][4], lsum[2][4];
#pragma unroll
  for (int mf = 0; mf < 2; mf++) {
#pragma unroll
    for (int dt = 0; dt < 4; dt++) {
      o[mf][dt][0] = 0.f; o[mf][dt][1] = 0.f; o[mf][dt][2] = 0.f; o[mf][dt][3] = 0.f;
    }
#pragma unroll
    for (int r = 0; r < 4; r++) { mrun[mf][r] = -1e30f; lsum[mf][r] = 0.f; }
  }

  const int nkv = (qbase + 95) >> 6;  // causal trip count for this tile

  bf8 kfA[4][2], kfB[4][2], vf[4][2];

  auto loadK = [&](bf8 (&kf)[4][2], int kvb) {
#pragma unroll
    for (int nt = 0; nt < 4; nt++)
#pragma unroll
      for (int ks = 0; ks < 2; ks++)
        kf[nt][ks] = *(const bf8*)(Kp + (size_t)(kvb + nt * 16 + lr) * 64 + ks * 32 + lg * 8);
  };

  auto iter = [&](bf8 (&cur)[4][2], bf8 (&nxt)[4][2], int kb) {
    const int kvb = kb * 64;

    // issue V loads for this tile NOW: latency hides under QK + softmax
#pragma unroll
    for (int dt = 0; dt < 4; dt++)
#pragma unroll
      for (int ks = 0; ks < 2; ks++)
        vf[dt][ks] = *(const bf8*)(Vp + (size_t)(dt * 16 + lr) * S + kvb + ks * 32 + lg * 8);

    f4 sc[2][4];
    __builtin_amdgcn_s_setprio(1);
#pragma unroll
    for (int mf = 0; mf < 2; mf++)
#pragma unroll
      for (int nt = 0; nt < 4; nt++) {
        f4 c;
        c[0] = 0.f; c[1] = 0.f; c[2] = 0.f; c[3] = 0.f;
        c = MFMA16(qf[mf][0], cur[nt][0], c);
        c = MFMA16(qf[mf][1], cur[nt][1], c);
        sc[mf][nt] = c;
      }
    __builtin_amdgcn_s_setprio(0);

    // prefetch next K tile: latency hides under softmax + PV
    if (kb + 1 < nkv) loadK(nxt, kvb + 64);

    const bool need_mask = (kvb + 63) > qbase;
    if (need_mask) {
#pragma unroll
      for (int mf = 0; mf < 2; mf++)
#pragma unroll
        for (int nt = 0; nt < 4; nt++)
#pragma unroll
          for (int r = 0; r < 4; r++) {
            const int q = qbase + mf * 16 + lg * 4 + r;
            const int kv = kvb + nt * 16 + lr;
            if (kv > q) sc[mf][nt][r] = -1e9f;
          }
    }

    // WAR guard: previous iteration's P reads fully drained (intra-wave)
    asm volatile("s_waitcnt lgkmcnt(0)" ::: "memory");

#pragma unroll
    for (int mf = 0; mf < 2; mf++) {
      float tmax[4];
#pragma unroll
      for (int r = 0; r < 4; r++) {
        float m0 = fmaxf(fmaxf(sc[mf][0][r], sc[mf][1][r]), fmaxf(sc[mf][2][r], sc[mf][3][r]));
#pragma unroll
        for (int j = 0; j < 4; j++) m0 = fmaxf(m0, __shfl_xor(m0, 1 << j));
        tmax[r] = m0;
      }
      // defer-max: only rescale when tile max grew past threshold (exp2 domain)
      float g = tmax[0] - mrun[mf][0];
#pragma unroll
      for (int r = 1; r < 4; r++) g = fmaxf(g, tmax[r] - mrun[mf][r]);
      if (__any(g > 8.0f)) {
#pragma unroll
        for (int r = 0; r < 4; r++) {
          const float mn = fmaxf(mrun[mf][r], tmax[r]);
          const float corr = __builtin_amdgcn_exp2f(mrun[mf][r] - mn);
          mrun[mf][r] = mn;
          lsum[mf][r] *= corr;
#pragma unroll
          for (int dt = 0; dt < 4; dt++) o[mf][dt][r] *= corr;
        }
      }
      // P = exp2(sc - m); per-lane partial sums; bf16 P to swizzled LDS
#pragma unroll
      for (int nt = 0; nt < 4; nt++)
#pragma unroll
        for (int r = 0; r < 4; r++) {
          const float p = __builtin_amdgcn_exp2f(sc[mf][nt][r] - mrun[mf][r]);
          lsum[mf][r] += p;
          const int row = mf * 16 + lg * 4 + r;
          const int boff = (row * 128 + (nt * 16 + lr) * 2) ^ ((row & 7) << 4);
          *(short*)(Pw + boff) = f2b_fast(p);
        }
    }

    // RAW guard: all lanes' P writes visible before fragment reads
    asm volatile("s_waitcnt lgkmcnt(0)" ::: "memory");

#pragma unroll
    for (int mf = 0; mf < 2; mf++) {
      bf8 pf[2];
#pragma unroll
      for (int ks = 0; ks < 2; ks++) {
        const int row = mf * 16 + lr;
        const int boff = (row * 128 + ks * 64 + lg * 16) ^ ((row & 7) << 4);
        pf[ks] = *(const bf8*)(Pw + boff);
      }
      __builtin_amdgcn_s_setprio(1);
#pragma unroll
      for (int dt = 0; dt < 4; dt++) {
        o[mf][dt] = MFMA16(pf[0], vf[dt][0], o[mf][dt]);
        o[mf][dt] = MFMA16(pf[1], vf[dt][1], o[mf][dt]);
      }
      __builtin_amdgcn_s_setprio(0);
    }
  };

  loadK(kfA, 0);
  for (int kb = 0; kb < nkv; kb += 2) {
    iter(kfA, kfB, kb);
    if (kb + 1 < nkv) iter(kfB, kfA, kb + 1);
  }

  // final cross-lane row-sum reduce (deferred from the main loop)
#pragma unroll
  for (int mf = 0; mf < 2; mf++)
#pragma unroll
    for (int r = 0; r < 4; r++) {
      float s = lsum[mf][r];
#pragma unroll
      for (int j = 0; j < 4; j++) s += __shfl_xor(s, 1 << j);
      lsum[mf][r] = s;
    }

  const int b = bh >> 4, h = bh & 15;
#pragma unroll
  for (int mf = 0; mf < 2; mf++)
#pragma unroll
    for (int r = 0; r < 4; r++) {
      const int q = qbase + mf * 16 + lg * 4 + r;
      const float inv = 1.0f / lsum[mf][r];
#pragma unroll
      for (int dt = 0; dt < 4; dt++) {
        const int d = dt * 16 + lr;
        AO[((size_t)b * 2048 + q) * 1024 + h * 64 + d] = f2b(o[mf][dt][r] * inv);
      }
    }
}

extern "C" void kernel_launch(void* const* d_in, const int* in_sizes, int n_in,
                              void* d_out, int out_size, void* d_ws, size_t ws_size,
                              hipStream_t stream) {
  const float* x  = (const float*)d_in[0];
  const float* wq = (const float*)d_in[1];
  const float* wk = (const float*)d_in[2];
  const float* wv = (const float*)d_in[3];
  const float* wo = (const float*)d_in[4];
  float* out = (float*)d_out;

  char* ws = (char*)d_ws;
  short*  Qb  = (short*)(ws);                       // 8 MB  [b][h][s][64] bf16 (pre-scaled)
  short*  Kb  = (short*)(ws + (8ull  << 20));       // 8 MB
  short*  VTb = (short*)(ws + (16ull << 20));       // 8 MB  [b][h][64][s] bf16
  short*  AOb = (short*)(ws + (24ull << 20));       // 8 MB  [b][s][1024] bf16 (aliases xb)
  short*  xb  = AOb;                                // xb dead before attn writes AOb
  short*  Wb  = (short*)(ws + (32ull << 20));       // 8 MB  [4][1024][1024] bf16
  float2* tab = (float2*)(ws + (40ull << 20));      // 512 KB rope table

  convert_kernel<<<4096, 256, 0, stream>>>(x, wq, wk, wv, wo, xb, Wb);
  rope_kernel<<<256, 256, 0, stream>>>(tab);
  gemm_kernel<0><<<dim3(32, 8, 3), 256, 0, stream>>>(
      xb, Wb, Qb, Kb, VTb, nullptr, tab);
  attn_kernel<<<dim3(32, 16), 256, 0, stream>>>(Qb, Kb, VTb, AOb);
  gemm_kernel<1><<<dim3(32, 8, 1), 256, 0, stream>>>(
      AOb, Wb, nullptr, nullptr, nullptr, out, nullptr);
}

// Round 4
// 134.958 us; speedup vs baseline: 1.5188x; 1.3438x over previous
//
#include <hip/hip_runtime.h>
#include <hip/hip_bf16.h>
#include <stdint.h>

typedef __attribute__((ext_vector_type(8))) short bf8;
typedef __attribute__((ext_vector_type(4))) float f4;

#define MFMA16(a, b, c) __builtin_amdgcn_mfma_f32_16x16x32_bf16((a), (b), (c), 0, 0, 0)

static __device__ __forceinline__ short f2b(float f) {
  uint32_t x = __float_as_uint(f);
  x += 0x7fffu + ((x >> 16) & 1u);
  return (short)(x >> 16);
}

// pack two nonnegative f32 into 2x bf16 (round-half-up, <0.5 ulp bias)
static __device__ __forceinline__ uint32_t pk2(float a, float b) {
  return ((__float_as_uint(a) + 0x8000u) >> 16) |
         ((__float_as_uint(b) + 0x8000u) & 0xffff0000u);
}

// rope table: tab[s*32 + i] = (cos(s*invf_i), sin(s*invf_i)), s<2048, i<32
__global__ void rope_kernel(float2* __restrict__ tab) {
  const int t = blockIdx.x * 256 + threadIdx.x;
  const int s = t >> 5, i = t & 31;
  const float inv = powf(10000.0f, -(float)i * (1.0f / 32.0f));
  const float ang = (float)s * inv;
  float sv, cv;
  sincosf(ang, &sv, &cv);
  tab[t] = make_float2(cv, sv);
}

// one-shot f32->bf16: x (4194304) -> xb; wq,wk,wv,wo (1048576 each) -> Wb[4][1<<20]
__global__ void convert_kernel(const float* __restrict__ x,
                               const float* __restrict__ wq, const float* __restrict__ wk,
                               const float* __restrict__ wv, const float* __restrict__ wo,
                               short* __restrict__ xb, short* __restrict__ Wb) {
  const size_t i = ((size_t)blockIdx.x * 256 + threadIdx.x) * 8;
  const float* __restrict__ src;
  short* __restrict__ dst;
  if (i < 4194304u) {
    src = x + i;
    dst = xb + i;
  } else {
    const size_t j = i - 4194304u;
    const int z = (int)(j >> 20);
    const size_t o = j & 1048575u;
    src = (z == 0 ? wq : z == 1 ? wk : z == 2 ? wv : wo) + o;
    dst = Wb + j;
  }
  const float4 a = *(const float4*)src;
  const float4 b = *(const float4*)(src + 4);
  bf8 v;
  v[0] = f2b(a.x); v[1] = f2b(a.y); v[2] = f2b(a.z); v[3] = f2b(a.w);
  v[4] = f2b(b.x); v[5] = f2b(b.y); v[6] = f2b(b.z); v[7] = f2b(b.w);
  *(bf8*)dst = v;
}

// C = A @ W^T, pure-bf16 inputs. 128x128 tiles, BK=64, 4 waves each 64x64.
// MODE 0: A = xb, W = Wb[z] (z = blockIdx.z in {0,1,2} = Wq,Wk,Wv)
//         z<2: RoPE epilogue -> Q/K as [b][h][s][64] bf16 (Q pre-scaled by 0.125*log2e)
//         z==2: V^T epilogue -> [b][h][64][s] bf16
// MODE 1: A = AOb, W = Wb[3] (Wo), f32 epilogue -> [m][n]
template <int MODE>
__launch_bounds__(256, 2)
__global__ void gemm_kernel(const short* __restrict__ Ab, const short* __restrict__ Wb,
                            short* __restrict__ Qo, short* __restrict__ Ko,
                            short* __restrict__ VTo, float* __restrict__ Fo,
                            const float2* __restrict__ rope) {
  constexpr int K = 1024;
  const int bm = blockIdx.x, bn = blockIdx.y;
  const int z = (MODE == 0) ? blockIdx.z : 3;
  const short* __restrict__ Bb = Wb + ((size_t)z << 20);

  __shared__ short As[128 * 64];
  __shared__ short Bs[128 * 64];

  const int tid = threadIdx.x;
  const int lane = tid & 63;
  const int wave = tid >> 6;
  const int wr = wave >> 1, wc = wave & 1;
  const int lg = lane >> 4, lr = lane & 15;

  f4 acc[4][4];
#pragma unroll
  for (int i = 0; i < 4; i++)
#pragma unroll
    for (int j = 0; j < 4; j++) {
      acc[i][j][0] = 0.f; acc[i][j][1] = 0.f;
      acc[i][j][2] = 0.f; acc[i][j][3] = 0.f;
    }

  const int kc = tid & 7;     // 16B k-chunk within 64-wide slice
  const int srow = tid >> 3;  // 0..31

  for (int k0 = 0; k0 < K; k0 += 64) {
    bf8 va[4], vb[4];
#pragma unroll
    for (int i = 0; i < 4; i++) {
      const int row = srow + i * 32;
      va[i] = *(const bf8*)(Ab + (size_t)(bm * 128 + row) * K + k0 + kc * 8);
      vb[i] = *(const bf8*)(Bb + (size_t)(bn * 128 + row) * K + k0 + kc * 8);
    }
#pragma unroll
    for (int i = 0; i < 4; i++) {
      const int row = srow + i * 32;
      const int lb = (row * 128 + kc * 16) ^ ((row & 7) << 4);
      *(bf8*)((char*)As + lb) = va[i];
      *(bf8*)((char*)Bs + lb) = vb[i];
    }
    __syncthreads();
#pragma unroll
    for (int kk = 0; kk < 2; kk++) {
      bf8 af[4], bb[4];
#pragma unroll
      for (int mi = 0; mi < 4; mi++) {
        const int row = wr * 64 + mi * 16 + lr;
        const int lb = (row * 128 + kk * 64 + lg * 16) ^ ((row & 7) << 4);
        af[mi] = *(const bf8*)((const char*)As + lb);
      }
#pragma unroll
      for (int ni = 0; ni < 4; ni++) {
        const int row = wc * 64 + ni * 16 + lr;
        const int lb = (row * 128 + kk * 64 + lg * 16) ^ ((row & 7) << 4);
        bb[ni] = *(const bf8*)((const char*)Bs + lb);
      }
      __builtin_amdgcn_s_setprio(1);
#pragma unroll
      for (int mi = 0; mi < 4; mi++)
#pragma unroll
        for (int ni = 0; ni < 4; ni++)
          acc[mi][ni] = MFMA16(af[mi], bb[ni], acc[mi][ni]);
      __builtin_amdgcn_s_setprio(0);
    }
    __syncthreads();
  }

  if (MODE == 1) {
#pragma unroll
    for (int mi = 0; mi < 4; mi++) {
      const int m0 = bm * 128 + wr * 64 + mi * 16 + lg * 4;
#pragma unroll
      for (int ni = 0; ni < 4; ni++) {
        const int n = bn * 128 + wc * 64 + ni * 16 + lr;
#pragma unroll
        for (int r = 0; r < 4; r++)
          Fo[(size_t)(m0 + r) * 1024 + n] = acc[mi][ni][r];
      }
    }
    return;
  }

  if (z == 2) {  // V^T: [b][h][64][s]
#pragma unroll
    for (int mi = 0; mi < 4; mi++) {
      const int m0 = bm * 128 + wr * 64 + mi * 16 + lg * 4;
      const int b = m0 >> 11, s0 = m0 & 2047;
#pragma unroll
      for (int ni = 0; ni < 4; ni++) {
        const int n = bn * 128 + wc * 64 + ni * 16 + lr;
        ushort4 pk;
        pk.x = (unsigned short)f2b(acc[mi][ni][0]);
        pk.y = (unsigned short)f2b(acc[mi][ni][1]);
        pk.z = (unsigned short)f2b(acc[mi][ni][2]);
        pk.w = (unsigned short)f2b(acc[mi][ni][3]);
        *(ushort4*)(VTo + ((size_t)((b * 16 + (n >> 6)) * 64 + (n & 63))) * 2048 + s0) = pk;
      }
    }
  } else {  // Q or K with RoPE: [b][h][s][64]
    short* __restrict__ Out = (z == 0) ? Qo : Ko;
    // Q gets the attention scale folded with log2(e) so softmax can use exp2
    const float qscale = (z == 0) ? 0.18033688011112042f : 1.0f;  // 0.125*log2(e)
#pragma unroll
    for (int mi = 0; mi < 4; mi++) {
      const int m0 = bm * 128 + wr * 64 + mi * 16 + lg * 4;
      const int b = m0 >> 11, s0 = m0 & 2047;
#pragma unroll
      for (int ni = 0; ni < 4; ni++) {
        const int n = bn * 128 + wc * 64 + ni * 16 + lr;
        const int h = n >> 6, d = n & 63;
        const float sgn = (d & 1) ? 1.0f : -1.0f;
#pragma unroll
        for (int r = 0; r < 4; r++) {
          const float v = acc[mi][ni][r];
          const float p = __shfl_xor(v, 1);  // partner head-dim (d^1)
          const float2 cs = rope[((s0 + r) << 5) + (d >> 1)];
          const float res = (v * cs.x + sgn * p * cs.y) * qscale;
          Out[((size_t)(b * 16 + h) * 2048 + (s0 + r)) * 64 + d] = f2b(res);
        }
      }
    }
  }
}

// Flash attention, causal. 4 waves/block; each wave owns one 32-row q-tile.
// Balanced tile set per block {qi, 31-qi, 32+qi, 63-qi}, rotated across wave slots.
// SWAPPED QK^T: st = MFMA(K, Q) so each lane holds 16 in-lane kv scores per q-row
// (q = lr) -> row reduce = in-lane fmax tree + 2 shfls (vs 32 shfl chains before).
// m/lsum state kept per-lane in swapped layout; redistribution to o-layout (q =
// lg*4+r) via __shfl only on rare rescale + once at end.
// K prefetched one tile ahead (single body + reg copy); V issued at iter head.
// Q pre-scaled by 0.125*log2e -> softmax in exp2 domain.
__launch_bounds__(256, 2)
__global__ void attn_kernel(const short* __restrict__ Qg, const short* __restrict__ Kg,
                            const short* __restrict__ Vg, short* __restrict__ AO) {
  const int S = 2048;
  const int bh = blockIdx.x, qi = blockIdx.y;
  const int lane = threadIdx.x & 63, wave = threadIdx.x >> 6;
  const int lg = lane >> 4, lr = lane & 15;
  const short* __restrict__ Qp = Qg + (size_t)bh * S * 64;
  const short* __restrict__ Kp = Kg + (size_t)bh * S * 64;
  const short* __restrict__ Vp = Vg + (size_t)bh * 64 * S;

  __shared__ short Pl[4][32 * 64];  // wave-private P tiles, XOR-swizzled
  char* const Pw = (char*)&Pl[wave][0];

  const int slot = (wave + qi) & 3;
  const int t = (slot == 0) ? qi : (slot == 1) ? (31 - qi)
              : (slot == 2) ? (32 + qi) : (63 - qi);
  const int qbase = t << 5;

  bf8 qf[2][2];
#pragma unroll
  for (int mf = 0; mf < 2; mf++)
#pragma unroll
    for (int ks = 0; ks < 2; ks++)
      qf[mf][ks] = *(const bf8*)(Qp + (size_t)(qbase + mf * 16 + lr) * 64 + ks * 32 + lg * 8);

  f4 o[2][4];
#pragma unroll
  for (int mf = 0; mf < 2; mf++)
#pragma unroll
    for (int dt = 0; dt < 4; dt++) {
      o[mf][dt][0] = 0.f; o[mf][dt][1] = 0.f; o[mf][dt][2] = 0.f; o[mf][dt][3] = 0.f;
    }
  // swapped-layout softmax state: q = qbase + mf*16 + lr (uniform across lg)
  float mrun[2] = {-1e30f, -1e30f};
  float lsum[2] = {0.f, 0.f};

  const int nkv = (qbase + 95) >> 6;  // causal trip count for this tile

  bf8 kf[4][2], kfN[4][2], vf[4][2];
#pragma unroll
  for (int nt = 0; nt < 4; nt++)
#pragma unroll
    for (int ks = 0; ks < 2; ks++)
      kf[nt][ks] = *(const bf8*)(Kp + (size_t)(nt * 16 + lr) * 64 + ks * 32 + lg * 8);

  for (int kb = 0; kb < nkv; kb++) {
    const int kvb = kb * 64;

    // issue V loads now: latency hides under QK + softmax
#pragma unroll
    for (int dt = 0; dt < 4; dt++)
#pragma unroll
      for (int ks = 0; ks < 2; ks++)
        vf[dt][ks] = *(const bf8*)(Vp + (size_t)(dt * 16 + lr) * S + kvb + ks * 32 + lg * 8);

    // swapped QK^T: st[nt][mf] = S^T[kv = kvb+nt*16+lg*4+r][q = qbase+mf*16+lr]
    f4 st[4][2];
    __builtin_amdgcn_s_setprio(1);
#pragma unroll
    for (int nt = 0; nt < 4; nt++)
#pragma unroll
      for (int mf = 0; mf < 2; mf++) {
        f4 c;
        c[0] = 0.f; c[1] = 0.f; c[2] = 0.f; c[3] = 0.f;
        c = MFMA16(kf[nt][0], qf[mf][0], c);
        c = MFMA16(kf[nt][1], qf[mf][1], c);
        st[nt][mf] = c;
      }
    __builtin_amdgcn_s_setprio(0);

    // prefetch next K tile: latency hides under softmax + PV
    const bool pre = (kb + 1 < nkv);
    if (pre) {
#pragma unroll
      for (int nt = 0; nt < 4; nt++)
#pragma unroll
        for (int ks = 0; ks < 2; ks++)
          kfN[nt][ks] = *(const bf8*)(Kp + (size_t)(kvb + 64 + nt * 16 + lr) * 64 + ks * 32 + lg * 8);
    }

    if ((kvb + 63) > qbase) {  // causal mask
#pragma unroll
      for (int nt = 0; nt < 4; nt++)
#pragma unroll
        for (int mf = 0; mf < 2; mf++)
#pragma unroll
          for (int r = 0; r < 4; r++) {
            const int kv = kvb + nt * 16 + lg * 4 + r;
            const int q = qbase + mf * 16 + lr;
            if (kv > q) st[nt][mf][r] = -1e9f;
          }
    }

    // per-q tile max: in-lane tree over 16 values + 2 cross-lg shfls
    float tmax[2];
#pragma unroll
    for (int mf = 0; mf < 2; mf++) {
      float m0 = st[0][mf][0];
#pragma unroll
      for (int nt = 0; nt < 4; nt++)
#pragma unroll
        for (int r = 0; r < 4; r++) m0 = fmaxf(m0, st[nt][mf][r]);
      m0 = fmaxf(m0, __shfl_xor(m0, 16));
      m0 = fmaxf(m0, __shfl_xor(m0, 32));
      tmax[mf] = m0;
    }
    // defer-max: rescale only when tile max grew past threshold (exp2 domain)
    const float g = fmaxf(tmax[0] - mrun[0], tmax[1] - mrun[1]);
    if (__any(g > 8.0f)) {
#pragma unroll
      for (int mf = 0; mf < 2; mf++) {
        const float mn = fmaxf(mrun[mf], tmax[mf]);
        const float corr = __builtin_amdgcn_exp2f(mrun[mf] - mn);
        mrun[mf] = mn;
        lsum[mf] *= corr;
#pragma unroll
        for (int r = 0; r < 4; r++) {
          const float co = __shfl(corr, (lg << 2) + r);  // o-layout q = lg*4+r
#pragma unroll
          for (int dt = 0; dt < 4; dt++) o[mf][dt][r] *= co;
        }
      }
    }

    // WAR guard: previous iteration's P reads fully drained (intra-wave)
    asm volatile("s_waitcnt lgkmcnt(0)" ::: "memory");

    // P = exp2(st - m); in-lane partial sums; pack 4 consecutive kv -> b64 store
#pragma unroll
    for (int mf = 0; mf < 2; mf++) {
      const int row = mf * 16 + lr;
      const int rowoff = row * 128;
      const int sw = (row & 7) << 4;
#pragma unroll
      for (int nt = 0; nt < 4; nt++) {
        const float p0 = __builtin_amdgcn_exp2f(st[nt][mf][0] - mrun[mf]);
        const float p1 = __builtin_amdgcn_exp2f(st[nt][mf][1] - mrun[mf]);
        const float p2 = __builtin_amdgcn_exp2f(st[nt][mf][2] - mrun[mf]);
        const float p3 = __builtin_amdgcn_exp2f(st[nt][mf][3] - mrun[mf]);
        lsum[mf] += (p0 + p1) + (p2 + p3);
        *(uint2*)(Pw + ((rowoff + nt * 32 + lg * 8) ^ sw)) = make_uint2(pk2(p0, p1), pk2(p2, p3));
      }
    }

    // RAW guard: all lanes' P writes visible before fragment reads
    asm volatile("s_waitcnt lgkmcnt(0)" ::: "memory");

#pragma unroll
    for (int mf = 0; mf < 2; mf++) {
      bf8 pf[2];
#pragma unroll
      for (int ks = 0; ks < 2; ks++) {
        const int row = mf * 16 + lr;
        const int boff = (row * 128 + ks * 64 + lg * 16) ^ ((row & 7) << 4);
        pf[ks] = *(const bf8*)(Pw + boff);
      }
      __builtin_amdgcn_s_setprio(1);
#pragma unroll
      for (int dt = 0; dt < 4; dt++) {
        o[mf][dt] = MFMA16(pf[0], vf[dt][0], o[mf][dt]);
        o[mf][dt] = MFMA16(pf[1], vf[dt][1], o[mf][dt]);
      }
      __builtin_amdgcn_s_setprio(0);
    }

    if (pre) {
#pragma unroll
      for (int nt = 0; nt < 4; nt++)
#pragma unroll
        for (int ks = 0; ks < 2; ks++)
          kf[nt][ks] = kfN[nt][ks];
    }
  }

  // finalize: cross-lg sum reduce in swapped layout, then redistribute 1/lsum
  float inv_o[2][4];
#pragma unroll
  for (int mf = 0; mf < 2; mf++) {
    float s = lsum[mf];
    s += __shfl_xor(s, 16);
    s += __shfl_xor(s, 32);
    const float inv = 1.0f / s;
#pragma unroll
    for (int r = 0; r < 4; r++) inv_o[mf][r] = __shfl(inv, (lg << 2) + r);
  }

  const int b = bh >> 4, h = bh & 15;
#pragma unroll
  for (int mf = 0; mf < 2; mf++)
#pragma unroll
    for (int r = 0; r < 4; r++) {
      const int q = qbase + mf * 16 + lg * 4 + r;
#pragma unroll
      for (int dt = 0; dt < 4; dt++) {
        const int d = dt * 16 + lr;
        AO[((size_t)b * 2048 + q) * 1024 + h * 64 + d] = f2b(o[mf][dt][r] * inv_o[mf][r]);
      }
    }
}

extern "C" void kernel_launch(void* const* d_in, const int* in_sizes, int n_in,
                              void* d_out, int out_size, void* d_ws, size_t ws_size,
                              hipStream_t stream) {
  const float* x  = (const float*)d_in[0];
  const float* wq = (const float*)d_in[1];
  const float* wk = (const float*)d_in[2];
  const float* wv = (const float*)d_in[3];
  const float* wo = (const float*)d_in[4];
  float* out = (float*)d_out;

  char* ws = (char*)d_ws;
  short*  Qb  = (short*)(ws);                       // 8 MB  [b][h][s][64] bf16 (pre-scaled)
  short*  Kb  = (short*)(ws + (8ull  << 20));       // 8 MB
  short*  VTb = (short*)(ws + (16ull << 20));       // 8 MB  [b][h][64][s] bf16
  short*  AOb = (short*)(ws + (24ull << 20));       // 8 MB  [b][s][1024] bf16 (aliases xb)
  short*  xb  = AOb;                                // xb dead before attn writes AOb
  short*  Wb  = (short*)(ws + (32ull << 20));       // 8 MB  [4][1024][1024] bf16
  float2* tab = (float2*)(ws + (40ull << 20));      // 512 KB rope table

  convert_kernel<<<4096, 256, 0, stream>>>(x, wq, wk, wv, wo, xb, Wb);
  rope_kernel<<<256, 256, 0, stream>>>(tab);
  gemm_kernel<0><<<dim3(32, 8, 3), 256, 0, stream>>>(
      xb, Wb, Qb, Kb, VTb, nullptr, tab);
  attn_kernel<<<dim3(32, 16), 256, 0, stream>>>(Qb, Kb, VTb, AOb);
  gemm_kernel<1><<<dim3(32, 8, 1), 256, 0, stream>>>(
      AOb, Wb, nullptr, nullptr, nullptr, out, nullptr);
}